// Round 5
// baseline (98.982 us; speedup 1.0000x reference)
//
#include <hip/hip_runtime.h>
#include <math.h>
#include <stdint.h>

#define N_QUBITS 4
#define N_LAYERS 6
#define NW (N_LAYERS * N_QUBITS)

// POD 4-float vector (no C++ ctors -> safe across address spaces)
typedef float vfloat4 __attribute__((ext_vector_type(4)));

// ---------------------------------------------------------------------------
// R14: FUSED kernel. R11/R13 showed the qeval inner loop is not the
// bottleneck (SPT amortization regressed; AS(4)/LDS-broadcast were neutral).
// Remaining controllable time is launch structure: qprep (1 tiny block, whole
// GPU idle) + a second dependent launch + the inter-kernel bubble. Fix: every
// block recomputes the 81-term coefficient table itself, straight into LDS.
//   prep cost/block ~2200 cy, overlapped across 8 resident blocks/CU
//   (~2 occupancy passes -> ~2 us wall), vs ~20 us of launch+idle+bubble.
// The per-thread x float4 load is issued FIRST so its HBM latency hides
// under the entire prep section. No workspace use at all.
// Eval side = validated R9/R10 structure (SPT=1, LDS uniform broadcast).
// ---------------------------------------------------------------------------
__global__ __launch_bounds__(256) void qfused_kernel(
    const float* __restrict__ x, const float* __restrict__ weights,
    float* __restrict__ out, int B)
{
    __shared__ float Wr[16][16];
    __shared__ float Wi[16][16];
    __shared__ float S[4][16][16];
    __shared__ vfloat4 Cs[81];
    __shared__ float wc[NW], ws[NW];

    const int tid = threadIdx.x;
    int b = blockIdx.x * 256 + tid;
    b = (b < B) ? b : (B - 1);   // clamp: wave-uniform, safe (dup writes same value)

    // Issue the per-thread x load first; latency hides under prep.
    const float4 xv = reinterpret_cast<const float4*>(x)[b];

    // --- prep phase 0: per-layer RX angles ---
    if (tid < NW) {
        float t = weights[tid] * 0.5f;
        wc[tid] = __cosf(t);
        ws[tid] = __sinf(t);
    }
    __syncthreads();

    // --- prep phase 1: threads 0..15 build column `tid` of W (16x16 cplx) ---
    if (tid < 16) {
        float re[16], im[16];
#pragma unroll
        for (int k = 0; k < 16; ++k) { re[k] = (k == tid) ? 1.f : 0.f; im[k] = 0.f; }
#pragma unroll 1
        for (int l = 0; l < N_LAYERS; ++l) {
#pragma unroll
            for (int q = 0; q < 4; ++q) {
                const float ct = wc[l * 4 + q], sn = ws[l * 4 + q];
                const int mask = 8 >> q;
#pragma unroll
                for (int idx = 0; idx < 16; ++idx) {
                    if (idx & mask) continue;
                    const int j = idx | mask;
                    float r0 = re[idx], u0 = im[idx], r1 = re[j], u1 = im[j];
                    re[idx] = ct * r0 + sn * u1; im[idx] = ct * u0 - sn * r1;
                    re[j]   = ct * r1 + sn * u0; im[j]   = ct * u1 - sn * r0;
                }
            }
#pragma unroll
            for (int q = 0; q < 4; ++q) {
                const int cm = 8 >> q, tm = 8 >> ((q + 1) & 3);
#pragma unroll
                for (int idx = 0; idx < 16; ++idx) {
                    if ((idx & cm) && !(idx & tm)) {
                        const int j = idx | tm;
                        float t0 = re[idx]; re[idx] = re[j]; re[j] = t0;
                        float t1 = im[idx]; im[idx] = im[j]; im[j] = t1;
                    }
                }
            }
        }
#pragma unroll
        for (int k = 0; k < 16; ++k) { Wr[k][tid] = re[k]; Wi[k][tid] = im[k]; }
    }
    __syncthreads();

    // --- prep phase 2: thread (i,j): S_q[i][j] = sum_k z_q(k) Re(W[k,i] W*[k,j]) ---
    {
        const int i = tid >> 4, j = tid & 15;
        float acc0 = 0.f, acc1 = 0.f, acc2 = 0.f, acc3 = 0.f;
#pragma unroll
        for (int k = 0; k < 16; ++k) {
            const float prod = Wr[k][i] * Wr[k][j] + Wi[k][i] * Wi[k][j];
            acc0 += (k & 8) ? -prod : prod;
            acc1 += (k & 4) ? -prod : prod;
            acc2 += (k & 2) ? -prod : prod;
            acc3 += (k & 1) ? -prod : prod;
        }
        S[0][i][j] = acc0; S[1][i][j] = acc1; S[2][i][j] = acc2; S[3][i][j] = acc3;
    }
    __syncthreads();

    // --- prep phase 3: Cs[t] = (1/16) sum_i (-1)^popc(i&zm) S_q[i][i^xm], q=0..3 ---
    if (tid < 81) {
        const int t1 = tid / 27, t2 = (tid / 9) % 3, t3 = (tid / 3) % 3, t4 = tid % 3;
        int zm = 0, xm = 0;
        if (t1 == 1) zm |= 8; else if (t1 == 2) xm |= 8;
        if (t2 == 1) zm |= 4; else if (t2 == 2) xm |= 4;
        if (t3 == 1) zm |= 2; else if (t3 == 2) xm |= 2;
        if (t4 == 1) zm |= 1; else if (t4 == 2) xm |= 1;
        vfloat4 cv;
#pragma unroll
        for (int q = 0; q < 4; ++q) {
            float acc = 0.f;
#pragma unroll
            for (int i = 0; i < 16; ++i) {
                const float v = S[q][i][i ^ xm];
                acc += (__popc(i & zm) & 1) ? -v : v;
            }
            cv[q] = acc * 0.0625f;
        }
        Cs[tid] = cv;
    }
    __syncthreads();

    // --- eval: out4 = sum_i u9[i] * ( sum_j C4[i*9+j] * w9[j] ) ---
    const float c0 = __cosf(xv.x), s0 = __sinf(xv.x);
    const float c1 = __cosf(xv.y), s1 = __sinf(xv.y);
    const float c2 = __cosf(xv.z), s2 = __sinf(xv.z);
    const float c3 = __cosf(xv.w), s3 = __sinf(xv.w);

    float u9[9], w9[9];
    u9[0] = 1.f;  u9[1] = c1;      u9[2] = s1;
    u9[3] = c0;   u9[4] = c0 * c1; u9[5] = c0 * s1;
    u9[6] = s0;   u9[7] = s0 * c1; u9[8] = s0 * s1;
    w9[0] = 1.f;  w9[1] = c3;      w9[2] = s3;
    w9[3] = c2;   w9[4] = c2 * c3; w9[5] = c2 * s3;
    w9[6] = s2;   w9[7] = s2 * c3; w9[8] = s2 * s3;

    float4 o = make_float4(0.f, 0.f, 0.f, 0.f);
#pragma unroll
    for (int i = 0; i < 9; ++i) {
        float4 t = make_float4(0.f, 0.f, 0.f, 0.f);
#pragma unroll
        for (int j = 0; j < 9; ++j) {
            const vfloat4 c = Cs[i * 9 + j];   // uniform addr -> LDS broadcast
            const float w = w9[j];
            t.x = fmaf(c.x, w, t.x);
            t.y = fmaf(c.y, w, t.y);
            t.z = fmaf(c.z, w, t.z);
            t.w = fmaf(c.w, w, t.w);
        }
        const float u = u9[i];
        o.x = fmaf(t.x, u, o.x);
        o.y = fmaf(t.y, u, o.y);
        o.z = fmaf(t.z, u, o.z);
        o.w = fmaf(t.w, u, o.w);
    }

    reinterpret_cast<float4*>(out)[b] = o;
}

extern "C" void kernel_launch(void* const* d_in, const int* in_sizes, int n_in,
                              void* d_out, int out_size, void* d_ws, size_t ws_size,
                              hipStream_t stream) {
    const float* x = (const float*)d_in[0];
    const float* weights = (const float*)d_in[1];
    float* out = (float*)d_out;
    const int B = in_sizes[0] / 4;

    const int grid = (B + 255) / 256;
    qfused_kernel<<<grid, 256, 0, stream>>>(x, weights, out, B);
}

// Round 6
// 80.407 us; speedup vs baseline: 1.2310x; 1.2310x over previous
//
#include <hip/hip_runtime.h>
#include <math.h>
#include <stdint.h>

#define N_QUBITS 4
#define N_LAYERS 6
#define NW (N_LAYERS * N_QUBITS)

// POD 4-float vector (no C++ ctors -> safe across address spaces)
typedef float vfloat4 __attribute__((ext_vector_type(4)));

// ---------------------------------------------------------------------------
// R15 = exact revert to the session-best two-kernel configuration (R0/R9,
// 80.5-80.7 us). Post-mortem of R10-R14: fill (~45 us, harness-owned, at 76%
// HBM roofline) + ~20 us fixed replay overhead + qeval ~9-12 us (at its
// ~8 us VALU+HBM floor) + qprep+bubble ~4 us. All four structural
// experiments (LDS broadcast, SPT=2, SPT=4, full fusion) attacked
// non-binding terms and regressed by paying occupancy or per-block-prep
// costs. This source is byte-identical in structure to the measured optimum.
// ---------------------------------------------------------------------------
__global__ __launch_bounds__(256) void qprep_kernel(
    const float* __restrict__ weights, float* __restrict__ Ctab)
{
    __shared__ float Wr[16][16];
    __shared__ float Wi[16][16];
    __shared__ float S[4][16][16];
    __shared__ float wc[NW], ws[NW];
    const int tid = threadIdx.x;
    if (tid < NW) {
        float t = weights[tid] * 0.5f;
        wc[tid] = __cosf(t);
        ws[tid] = __sinf(t);
    }
    __syncthreads();

    // Phase 1: threads 0..15 build column `tid` of W
    if (tid < 16) {
        float re[16], im[16];
#pragma unroll
        for (int k = 0; k < 16; ++k) { re[k] = (k == tid) ? 1.f : 0.f; im[k] = 0.f; }
#pragma unroll 1
        for (int l = 0; l < N_LAYERS; ++l) {
#pragma unroll
            for (int q = 0; q < 4; ++q) {
                const float ct = wc[l * 4 + q], sn = ws[l * 4 + q];
                const int mask = 8 >> q;
#pragma unroll
                for (int idx = 0; idx < 16; ++idx) {
                    if (idx & mask) continue;
                    const int j = idx | mask;
                    float r0 = re[idx], u0 = im[idx], r1 = re[j], u1 = im[j];
                    re[idx] = ct * r0 + sn * u1; im[idx] = ct * u0 - sn * r1;
                    re[j]   = ct * r1 + sn * u0; im[j]   = ct * u1 - sn * r0;
                }
            }
#pragma unroll
            for (int q = 0; q < 4; ++q) {
                const int cm = 8 >> q, tm = 8 >> ((q + 1) & 3);
#pragma unroll
                for (int idx = 0; idx < 16; ++idx) {
                    if ((idx & cm) && !(idx & tm)) {
                        const int j = idx | tm;
                        float t0 = re[idx]; re[idx] = re[j]; re[j] = t0;
                        float t1 = im[idx]; im[idx] = im[j]; im[j] = t1;
                    }
                }
            }
        }
#pragma unroll
        for (int k = 0; k < 16; ++k) { Wr[k][tid] = re[k]; Wi[k][tid] = im[k]; }
    }
    __syncthreads();

    // Phase 2: thread (i,j): S_q[i][j] = sum_k z_q(k) Re(W[k,i] conj(W[k,j]))
    {
        const int i = tid >> 4, j = tid & 15;
        float acc0 = 0.f, acc1 = 0.f, acc2 = 0.f, acc3 = 0.f;
#pragma unroll
        for (int k = 0; k < 16; ++k) {
            const float prod = Wr[k][i] * Wr[k][j] + Wi[k][i] * Wi[k][j];
            acc0 += (k & 8) ? -prod : prod;
            acc1 += (k & 4) ? -prod : prod;
            acc2 += (k & 2) ? -prod : prod;
            acc3 += (k & 1) ? -prod : prod;
        }
        S[0][i][j] = acc0; S[1][i][j] = acc1; S[2][i][j] = acc2; S[3][i][j] = acc3;
    }
    __syncthreads();

    // Phase 3: C_q[t] = (1/16) sum_i (-1)^popc(i&zm) S_q[i][i^xm]
    if (tid < 81) {
        const int t1 = tid / 27, t2 = (tid / 9) % 3, t3 = (tid / 3) % 3, t4 = tid % 3;
        int zm = 0, xm = 0;
        if (t1 == 1) zm |= 8; else if (t1 == 2) xm |= 8;
        if (t2 == 1) zm |= 4; else if (t2 == 2) xm |= 4;
        if (t3 == 1) zm |= 2; else if (t3 == 2) xm |= 2;
        if (t4 == 1) zm |= 1; else if (t4 == 2) xm |= 1;
#pragma unroll
        for (int q = 0; q < 4; ++q) {
            float acc = 0.f;
#pragma unroll
            for (int i = 0; i < 16; ++i) {
                const float v = S[q][i][i ^ xm];
                acc += (__popc(i & zm) & 1) ? -v : v;
            }
            Ctab[tid * 4 + q] = acc * 0.0625f;   // float4-per-term layout
        }
    }
}

// ---------------------------------------------------------------------------
// Main kernel: out4 = sum_i u9[i] * ( sum_j C4[i*9+j] * w9[j] ).
// Coefficient table read through the CONSTANT address space (4): uniform
// AS(4) loads take the scalar path where selected; per-lane L1 broadcast
// otherwise. This is the configuration that measured 80.5/80.7 us.
// ---------------------------------------------------------------------------
__global__ __launch_bounds__(256, 6) void qeval_kernel(
    const float* __restrict__ x, const float* __restrict__ Ctab,
    float* __restrict__ out, int B)
{
    int b = blockIdx.x * 256 + threadIdx.x;
    b = (b < B) ? b : (B - 1);   // clamp: wave-uniform control flow

    const float4 xv = reinterpret_cast<const float4*>(x)[b];
    const float c0 = __cosf(xv.x), s0 = __sinf(xv.x);
    const float c1 = __cosf(xv.y), s1 = __sinf(xv.y);
    const float c2 = __cosf(xv.z), s2 = __sinf(xv.z);
    const float c3 = __cosf(xv.w), s3 = __sinf(xv.w);

    // u9[t1*3+t2] = v0[t1]*v1[t2];  w9[t3*3+t4] = v2[t3]*v3[t4]
    float u9[9], w9[9];
    u9[0] = 1.f;  u9[1] = c1;      u9[2] = s1;
    u9[3] = c0;   u9[4] = c0 * c1; u9[5] = c0 * s1;
    u9[6] = s0;   u9[7] = s0 * c1; u9[8] = s0 * s1;
    w9[0] = 1.f;  w9[1] = c3;      w9[2] = s3;
    w9[3] = c2;   w9[4] = c2 * c3; w9[5] = c2 * s3;
    w9[6] = s2;   w9[7] = s2 * c3; w9[8] = s2 * s3;

    // Constant-address-space view of the table -> scalar (s_load) path.
    const __attribute__((address_space(4))) vfloat4* Cc =
        (const __attribute__((address_space(4))) vfloat4*)(unsigned long long)Ctab;

    float4 o = make_float4(0.f, 0.f, 0.f, 0.f);
#pragma unroll
    for (int i = 0; i < 9; ++i) {
        float4 t = make_float4(0.f, 0.f, 0.f, 0.f);
#pragma unroll
        for (int j = 0; j < 9; ++j) {
            const vfloat4 c = Cc[i * 9 + j];   // uniform AS(4) -> s_load_dwordx4
            const float w = w9[j];
            t.x = fmaf(c.x, w, t.x);
            t.y = fmaf(c.y, w, t.y);
            t.z = fmaf(c.z, w, t.z);
            t.w = fmaf(c.w, w, t.w);
        }
        const float u = u9[i];
        o.x = fmaf(t.x, u, o.x);
        o.y = fmaf(t.y, u, o.y);
        o.z = fmaf(t.z, u, o.z);
        o.w = fmaf(t.w, u, o.w);
    }

    reinterpret_cast<float4*>(out)[b] = o;
}

extern "C" void kernel_launch(void* const* d_in, const int* in_sizes, int n_in,
                              void* d_out, int out_size, void* d_ws, size_t ws_size,
                              hipStream_t stream) {
    const float* x = (const float*)d_in[0];
    const float* weights = (const float*)d_in[1];
    float* out = (float*)d_out;
    float* Ctab = (float*)d_ws;   // 324 floats, float4-per-term
    const int B = in_sizes[0] / 4;

    qprep_kernel<<<1, 256, 0, stream>>>(weights, Ctab);

    const int grid = (B + 255) / 256;
    qeval_kernel<<<grid, 256, 0, stream>>>(x, Ctab, out, B);
}